// Round 5
// baseline (289.107 us; speedup 1.0000x reference)
//
#include <hip/hip_runtime.h>
#include <math.h>

// Problem constants (from reference setup_inputs / GRID construction)
#define B_DIM  2
#define NCAM   6
#define D_DIM  48
#define H_DIM  28
#define W_DIM  60
#define C_DIM  64
#define X_DIM  128
#define Y_DIM  128
#define Z_DIM  4
#define NCELL  (B_DIM * X_DIM * Y_DIM)   // 32768 BEV cells
#define FR_CAM ((size_t)D_DIM * H_DIM * W_DIM * C_DIM)

// ---------------------------------------------------------------------------
// v4. v3 measured 288.6us (-26.1 vs v1) — bigger than the +13us kernel model
// predicted, so the v1 scratch-GJ was ~2us/block serial, i.e. kernel was
// ~35us and is now ~8us. Remaining controllable cost is (a) 8192 redundant
// per-block Gauss-Jordan setups + their barrier (~2-4us amortized),
// (b) hot-cell gather tail (~2-3us, already depth-2 pipelined),
// (c) irreducible 8.4MB output write + geometry (~2.5us).
//
// v4 removes (a): a 1-block pre-kernel runs the SAME register-only
// Gauss-Jordan code (bit-identical Ms values) and writes the 12 combined
// 3x4 matrices to d_ws; the main kernel reads its 48B matrix row with three
// float4 loads (L2-broadcast) — no setup phase, no setup barrier. Gather /
// geometry / LDS-transpose store are byte-for-byte the validated v3 code.
// Two launches on one stream: ordered, no host sync (graph-capture safe).
// ---------------------------------------------------------------------------

__device__ __forceinline__ void gather_issue(float* v, int pk,
                                             const float* __restrict__ fbase) {
    int kn = (pk >> 24) & 0xff;
    int zi = ((pk >> 16) & 0xff) - 1;
    int yi = ((pk >> 8)  & 0xff) - 1;
    int xi = (pk & 0xff) - 1;
    const float* fb = fbase + (size_t)kn * FR_CAM;
#pragma unroll
    for (int dz = 0; dz < 2; dz++) {
        int zc = min(max(zi + dz, 0), D_DIM - 1);
#pragma unroll
        for (int dy = 0; dy < 2; dy++) {
            int yc = min(max(yi + dy, 0), H_DIM - 1);
#pragma unroll
            for (int dx = 0; dx < 2; dx++) {
                int xc = min(max(xi + dx, 0), W_DIM - 1);
                v[dz * 4 + dy * 2 + dx] =
                    fb[(((size_t)zc * H_DIM + yc) * W_DIM + xc) * C_DIM];
            }
        }
    }
}

__device__ __forceinline__ void gather_consume(float& acc, const float* v, int pk,
                                               float kfx, float kfy, float kfz) {
    int zi = ((pk >> 16) & 0xff) - 1;
    int yi = ((pk >> 8)  & 0xff) - 1;
    int xi = (pk & 0xff) - 1;
    float wx[2] = {1.0f - kfx, kfx};
    float wy[2] = {1.0f - kfy, kfy};
    float wz[2] = {1.0f - kfz, kfz};
#pragma unroll
    for (int dz = 0; dz < 2; dz++) {
        int zz = zi + dz;
        bool bz = (zz >= 0) && (zz <= D_DIM - 1);
#pragma unroll
        for (int dy = 0; dy < 2; dy++) {
            int yy = yi + dy;
            bool by = (yy >= 0) && (yy <= H_DIM - 1);
            float wzy = wz[dz] * wy[dy];
#pragma unroll
            for (int dx = 0; dx < 2; dx++) {
                int xx = xi + dx;
                bool bx = (xx >= 0) && (xx <= W_DIM - 1);
                // exact same product order as validated kernel: (wz*wy)*wx
                float w = (bz && by && bx) ? (wzy * wx[dx]) : 0.0f;
                acc += w * v[dz * 4 + dy * 2 + dx];
            }
        }
    }
}

// ---- pre-kernel: build the 12 combined matrices once (same code as the
// validated per-block setup -> bit-identical values) ----
__global__ __launch_bounds__(64) void build_matrices(
        const float* __restrict__ intr,
        const float* __restrict__ l2s,
        float* __restrict__ ws) {
    int t = threadIdx.x;
    if (t >= B_DIM * NCAM) return;
    float A[4][8];
    const float* L = l2s + t * 16;
#pragma unroll
    for (int i = 0; i < 4; i++) {
#pragma unroll
        for (int jj = 0; jj < 4; jj++) A[i][jj] = L[i * 4 + jj];
#pragma unroll
        for (int jj = 0; jj < 4; jj++) A[i][4 + jj] = (i == jj) ? 1.0f : 0.0f;
    }
#pragma unroll
    for (int col = 0; col < 4; col++) {
        int p = col;
        float mx = fabsf(A[col][col]);
#pragma unroll
        for (int r = col + 1; r < 4; r++) {
            float v = fabsf(A[r][col]);
            if (v > mx) { mx = v; p = r; }
        }
        // Branchless pivot swap, statically indexed -> A stays in VGPRs.
#pragma unroll
        for (int r = col + 1; r < 4; r++) {
            bool sw = (p == r);
#pragma unroll
            for (int jj = 0; jj < 8; jj++) {
                float a = A[col][jj], bsw = A[r][jj];
                A[col][jj] = sw ? bsw : a;
                A[r][jj]   = sw ? a : bsw;
            }
        }
        float inv = 1.0f / A[col][col];
#pragma unroll
        for (int jj = 0; jj < 8; jj++) A[col][jj] *= inv;
#pragma unroll
        for (int r = 0; r < 4; r++) {
            if (r == col) continue;
            float f = A[r][col];
#pragma unroll
            for (int jj = 0; jj < 8; jj++) A[r][jj] -= f * A[col][jj];
        }
    }
    const float* K = intr + t * 9;
#pragma unroll
    for (int r = 0; r < 3; r++) {
#pragma unroll
        for (int c = 0; c < 4; c++) {
            float s = 0.0f;
#pragma unroll
            for (int k = 0; k < 3; k++) s += K[r * 3 + k] * A[k][4 + c];
            ws[t * 12 + r * 4 + c] = s;
        }
    }
}

__global__ __launch_bounds__(256) void frustum_to_bev_fused(
        const float* __restrict__ frustum,
        const float* __restrict__ Msg,     // 12 matrices from pre-kernel
        float* __restrict__ out) {
    __shared__ float accs[4][65];   // +1 pad: conflict-light transpose read

    int t = threadIdx.x;
    int wave = (blockIdx.x << 2) | (t >> 6);   // cell id, 0..32767
    int lane = t & 63;                         // channel c in gather phase
    int b = wave >> 14;
    int y = (wave >> 7) & 127;
    int x = wave & 127;

    float px = 0.75f * (float)x - 47.625f;     // voxel-center lidar coords
    float py = 0.75f * (float)y - 47.625f;

    // ---- geometry: lane j in [0,24) owns sample (n=j>>2, z=j&3) ----
    int j  = (lane < NCAM * Z_DIM) ? lane : 0;
    int n  = j >> 2;
    int z  = j & 3;
    // 48B matrix row, 16B-aligned: three float4 loads (L2-broadcast, uniform
    // within each 4-lane group)
    const float4* mrow = (const float4*)(Msg + (b * NCAM + n) * 12);
    float4 mA = mrow[0], mB = mrow[1], mC = mrow[2];
    float pz = 2.0f * (float)z - 3.0f;                    // {-3,-1,1,3}
    float uu = mA.x * px + mA.y * py + mA.z * pz + mA.w;
    float vv = mB.x * px + mB.y * py + mB.z * pz + mB.w;
    float dd = mC.x * px + mC.y * py + mC.z * pz + mC.w;

    // identical expressions to the validated kernels (align_corners=True)
    float ix = (uu / dd) * (59.0f / 60.0f);
    float iy = (vv / dd) * (27.0f / 28.0f);
    float iz = (dd - 2.0f) * (47.0f / 48.0f);

    bool valid = (lane < NCAM * Z_DIM) &&
                 (ix > -1.0f) && (ix < 60.0f) &&
                 (iy > -1.0f) && (iy < 28.0f) &&
                 (iz > -1.0f) && (iz < 48.0f);   // NaN (dd~0) fails -> invalid

    float xf = floorf(ix), yf = floorf(iy), zf = floorf(iz);
    float fx = ix - xf, fy = iy - yf, fz = iz - zf;
    int packed = (n << 24) | ((((int)zf + 1) & 0xff) << 16)
               | ((((int)yf + 1) & 0xff) << 8) | (((int)xf + 1) & 0xff);

    unsigned long long mask = __ballot(valid);

    // ---- gather: lanes = channels; valid samples in ascending (n,z) order,
    // depth-2 pipelined (issue k+1's loads before consuming k). ----
    float acc = 0.0f;
    const float* fbase = frustum + (size_t)b * NCAM * FR_CAM + lane;

    if (mask) {
        int k = __ffsll(mask) - 1; mask &= mask - 1;
        int   cpk = __shfl(packed, k);
        float cfx = __shfl(fx, k), cfy = __shfl(fy, k), cfz = __shfl(fz, k);
        float cv[8];
        gather_issue(cv, cpk, fbase);
        while (mask) {
            int k2 = __ffsll(mask) - 1; mask &= mask - 1;
            int   npk = __shfl(packed, k2);
            float nfx = __shfl(fx, k2), nfy = __shfl(fy, k2), nfz = __shfl(fz, k2);
            float nv[8];
            gather_issue(nv, npk, fbase);
            gather_consume(acc, cv, cpk, cfx, cfy, cfz);
            cpk = npk; cfx = nfx; cfy = nfy; cfz = nfz;
#pragma unroll
            for (int i = 0; i < 8; i++) cv[i] = nv[i];
        }
        gather_consume(acc, cv, cpk, cfx, cfy, cfz);
    }

    // ---- store: transpose through LDS so each 4-lane quad writes 16B
    // contiguous at out[b][c][y][x0..x0+3] (block's 4 waves = 4 consecutive x)
    accs[t >> 6][lane] = acc;
    __syncthreads();

    int cellbase = blockIdx.x << 2;
    int bb = cellbase >> 14;
    int yy = (cellbase >> 7) & 127;
    int x0 = cellbase & 127;
    int c  = t >> 2;
    int xi = t & 3;
    out[(((size_t)bb * C_DIM + c) * Y_DIM + yy) * X_DIM + x0 + xi] = accs[xi][c];
}

extern "C" void kernel_launch(void* const* d_in, const int* in_sizes, int n_in,
                              void* d_out, int out_size, void* d_ws, size_t ws_size,
                              hipStream_t stream) {
    const float* frustum = (const float*)d_in[0];  // [2,6,48,28,60,64] f32
    const float* intr    = (const float*)d_in[1];  // [2,6,3,3] f32
    const float* l2s     = (const float*)d_in[2];  // [2,6,4,4] f32
    float* out = (float*)d_out;                    // [2,64,128,128] f32
    float* ws  = (float*)d_ws;                     // 12 * 12 floats used

    // 1) build the 12 combined matrices once (1 tiny block)
    build_matrices<<<1, 64, 0, stream>>>(intr, l2s, ws);
    // 2) 32768 cells, 1 cell per wave, 4 waves per 256-thread block
    frustum_to_bev_fused<<<NCELL / 4, 256, 0, stream>>>(frustum, ws, out);
}